// Round 3
// baseline (267.152 us; speedup 1.0000x reference)
//
#include <hip/hip_runtime.h>
#include <math.h>

// InteractionGate: N=500000 agents, H=64, D=32.
// Reduction: d1 == 0 always; d2[i] = ||goal[i]-position[i]||;
// new_h[i][j] = sigmoid(C[j] + d2[i]*Wd[j] + dot(h[i], W2[j][:])), W2[j][k]=W_fc[j][64+k].
// h_out[idx] = h[idx]. goal_out (64) computed once (block 0).
//
// R3: single fused kernel. Weights staged in LDS in MFMA-A-frag layout
// (R1/R2 post-mortem: VGPR_Count=48 proved the compiler rematerializes
// register-resident weight frags as per-iteration divergent global gathers —
// LDS makes the reload path cheap and conflict-free). Operands swapped
// (A=weights m=out-dim, B=h-tile n=agent) so the epilogue is 4 dwordx4
// nontemporal stores and d2 needs no shuffle. Prefetch-depth-1 pipeline.

#define AH 64
#define AD 32

typedef __attribute__((ext_vector_type(8))) short bf16x8;
typedef __attribute__((ext_vector_type(4))) float f32x4;
typedef __attribute__((ext_vector_type(2))) float f32x2;

__device__ __forceinline__ float sigmoid_fast(float x) {
    return 1.0f / (1.0f + __expf(-x));
}

__device__ __forceinline__ short f2bf(float f) {
    union { float f; unsigned u; } v; v.f = f;
    unsigned r = v.u + 0x7fffu + ((v.u >> 16) & 1u);
    return (short)(r >> 16);
}

__global__ __launch_bounds__(256, 4) void ig_fused(
    const float* __restrict__ h,      // N x 64
    const float* __restrict__ ghs,    // 64
    const float* __restrict__ goal,   // N x 2
    const float* __restrict__ pos,    // N x 2
    const float* __restrict__ W_emb,  // 32 x 2
    const float* __restrict__ b_emb,  // 32
    const float* __restrict__ W_fc,   // 64 x 192
    const float* __restrict__ b_fc,   // 64
    const int*   __restrict__ idx_p,
    float* __restrict__ out,          // N*64 h_out, then 64 goal_out
    int N, int n_tiles, int total_waves)
{
    // Weight A-frags: wlds[f=mg*2+c][lane] = 8 bf16 of W2[mg*16+(lane&15)][c*32+(lane>>4)*8 + 0..7]
    __shared__ bf16x8 wlds[8][64];                 // 8 KB
    __shared__ __align__(16) float cw[128];        // C[0:64], Wd[64:128]

    const int tid  = threadIdx.x;
    const int w    = tid >> 6;
    const int lane = tid & 63;
    const int m15  = lane & 15;
    const int q    = lane >> 4;
    const int idx  = idx_p[0];

    // ---------------- setup phase ----------------
    if (w == 0) {
        // Lane l computes C[l], Wd[l]; block 0 also writes goal_out[l].
        const int l = lane;
        const float* wrow = W_fc + l * 192;
        const f32x4* w4  = (const f32x4*)wrow;          // W2h part: k=0..63 (h_idx slot)
        const f32x4* wg4 = (const f32x4*)(wrow + AH);   // h slot (goal uses ghs here)
        const f32x4* h4  = (const f32x4*)(h + (size_t)idx * AH);
        const f32x4* g4  = (const f32x4*)ghs;
        float c = b_fc[l], g = b_fc[l];
        #pragma unroll
        for (int m = 0; m < 16; ++m) {
            const f32x4 hv = h4[m], wv = w4[m];
            const float d = hv[0]*wv[0] + hv[1]*wv[1] + hv[2]*wv[2] + hv[3]*wv[3];
            c += d; g += d;
            const f32x4 gv = g4[m], wv2 = wg4[m];
            g += gv[0]*wv2[0] + gv[1]*wv2[1] + gv[2]*wv2[2] + gv[3]*wv2[3];
        }
        const float px = pos[(size_t)idx*2+0], py = pos[(size_t)idx*2+1];
        const float gx = goal[(size_t)idx*2+0], gy = goal[(size_t)idx*2+1];
        const float dgx = px - gx, dgy = py - gy;
        const float dg = sqrtf(dgx*dgx + dgy*dgy);
        const float* wd1 = wrow + 128;   // d1e slot
        const float* wd2 = wrow + 160;   // d2e slot
        float wd = 0.f;
        #pragma unroll
        for (int k = 0; k < AD; ++k) {
            const float wsum = W_emb[2*k] + W_emb[2*k+1];
            const float be   = b_emb[k];
            const float w12  = wd1[k] + wd2[k];
            c  += be * w12;              // d1e==b_emb plus b_emb part of d2e
            wd += wsum * wd2[k];
            g  += (dg * wsum + be) * w12;
        }
        cw[l]      = c;
        cw[64 + l] = wd;
        if (blockIdx.x == 0) out[(size_t)N * AH + l] = sigmoid_fast(g);
    } else {
        // Waves 1..3 build the 8 weight frags (f = w-1, w+2, w+5 pattern).
        for (int f = w - 1; f < 8; f += 3) {
            const int mg = f >> 1, c = f & 1;
            const float* src = W_fc + (size_t)(mg*16 + m15) * 192 + AH + c*32 + q*8;
            const f32x4 s0 = *(const f32x4*)(src);
            const f32x4 s1 = *(const f32x4*)(src + 4);
            bf16x8 b;
            #pragma unroll
            for (int j = 0; j < 4; ++j) { b[j] = f2bf(s0[j]); b[4+j] = f2bf(s1[j]); }
            wlds[f][lane] = b;
        }
    }
    __syncthreads();

    // ---------------- main loop ----------------
    const int wid = blockIdx.x * 4 + w;

    int t = wid;
    f32x4 b0 = {}, b1 = {}, b2 = {}, b3 = {};
    f32x2 gv = {}, pv = {};
    if (t < n_tiles) {
        const int n0 = t * 16 + m15;
        const float* hr = h + (size_t)n0 * AH;
        b0 = *(const f32x4*)(hr + q*8);
        b1 = *(const f32x4*)(hr + q*8 + 4);
        b2 = *(const f32x4*)(hr + 32 + q*8);
        b3 = *(const f32x4*)(hr + 32 + q*8 + 4);
        gv = *(const f32x2*)(goal + 2*(size_t)n0);
        pv = *(const f32x2*)(pos  + 2*(size_t)n0);
    }

    while (t < n_tiles) {
        const int tn = t + total_waves;
        const int tload = (tn < n_tiles) ? tn : t;   // clamp: last iter re-reads (harmless)
        const int nl = tload * 16 + m15;
        const float* hrn = h + (size_t)nl * AH;
        const f32x4 nb0 = *(const f32x4*)(hrn + q*8);
        const f32x4 nb1 = *(const f32x4*)(hrn + q*8 + 4);
        const f32x4 nb2 = *(const f32x4*)(hrn + 32 + q*8);
        const f32x4 nb3 = *(const f32x4*)(hrn + 32 + q*8 + 4);
        const f32x2 ngv = *(const f32x2*)(goal + 2*(size_t)nl);
        const f32x2 npv = *(const f32x2*)(pos  + 2*(size_t)nl);

        // ---- compute tile t ----
        const int agent = t * 16 + m15;          // this lane's output column
        const float dx = gv[0] - pv[0], dy = gv[1] - pv[1];
        const float d2v = sqrtf(dx*dx + dy*dy);

        bf16x8 bf0, bf1;
        #pragma unroll
        for (int j = 0; j < 4; ++j) {
            bf0[j] = f2bf(b0[j]); bf0[4+j] = f2bf(b1[j]);
            bf1[j] = f2bf(b2[j]); bf1[4+j] = f2bf(b3[j]);
        }

        const size_t rb = (size_t)agent * AH;
        #pragma unroll
        for (int mg = 0; mg < 4; ++mg) {
            const f32x4 c4 = *(const f32x4*)&cw[mg*16 + q*4];
            const f32x4 d4 = *(const f32x4*)&cw[64 + mg*16 + q*4];
            f32x4 acc;
            #pragma unroll
            for (int r = 0; r < 4; ++r) acc[r] = c4[r] + d2v * d4[r];
            acc = __builtin_amdgcn_mfma_f32_16x16x32_bf16(wlds[mg*2+0][lane], bf0, acc, 0, 0, 0);
            acc = __builtin_amdgcn_mfma_f32_16x16x32_bf16(wlds[mg*2+1][lane], bf1, acc, 0, 0, 0);

            f32x4 vv;
            #pragma unroll
            for (int r = 0; r < 4; ++r) vv[r] = sigmoid_fast(acc[r]);
            if (agent == idx) vv = *(const f32x4*)(h + rb + mg*16 + q*4);  // keep original row
            __builtin_nontemporal_store(vv, (f32x4*)(out + rb + mg*16 + q*4));
        }

        t = tn;
        b0 = nb0; b1 = nb1; b2 = nb2; b3 = nb3;
        gv = ngv; pv = npv;
    }
}

extern "C" void kernel_launch(void* const* d_in, const int* in_sizes, int n_in,
                              void* d_out, int out_size, void* d_ws, size_t ws_size,
                              hipStream_t stream) {
    const float* h     = (const float*)d_in[0];
    const float* ghs   = (const float*)d_in[1];
    const float* goal  = (const float*)d_in[2];
    const float* pos   = (const float*)d_in[3];
    const float* W_emb = (const float*)d_in[4];
    const float* b_emb = (const float*)d_in[5];
    const float* W_fc  = (const float*)d_in[6];
    const float* b_fc  = (const float*)d_in[7];
    const int*   idx_p = (const int*)d_in[8];

    const int N = in_sizes[0] / AH;          // 500000
    float* out = (float*)d_out;              // N*64 h_out, then 64 goal_out

    const int n_tiles = N / 16;              // 31250 (exact)
    const int blocks = 1280;                 // ~5 blocks/CU, persistent grid-stride
    const int total_waves = blocks * 4;
    ig_fused<<<blocks, 256, 0, stream>>>(h, ghs, goal, pos, W_emb, b_emb, W_fc, b_fc,
                                         idx_p, out, N, n_tiles, total_waves);
}

// Round 4
// 256.521 us; speedup vs baseline: 1.0414x; 1.0414x over previous
//
#include <hip/hip_runtime.h>
#include <math.h>

// InteractionGate: N=500000 agents, H=64, D=32.
// Reduction: d1 == 0 always; d2[i] = ||goal[i]-position[i]||;
// new_h[i][j] = sigmoid(C[j] + d2[i]*Wd[j] + dot(h[i], W2[j][:])), W2[j][k]=W_fc[j][64+k].
// h_out[idx] = h[idx]. goal_out (64) computed once.
//
// R4: R3 minus the two store-path mistakes. Post-mortem R3: nontemporal +
// 64B-scatter stores inflated WRITE_SIZE 125->157MB (L2 write-combining
// bypassed). Plain stores restore L2 merging. Precompute split out again and
// extended to pre-build the bf16 weight A-frags in d_ws, so main blocks stage
// 8.5KB from ws instead of gathering 48KB W_fc each. Grid = 1024 blocks
// (exact 4 blocks/CU fit at VGPR<=64). Sigmoid uses v_rcp_f32.

#define AH 64
#define AD 32

typedef __attribute__((ext_vector_type(8))) short bf16x8;
typedef __attribute__((ext_vector_type(4))) float f32x4;
typedef __attribute__((ext_vector_type(2))) float f32x2;

__device__ __forceinline__ float sigmoid_fast(float x) {
    return __builtin_amdgcn_rcpf(1.0f + __expf(-x));
}

__device__ __forceinline__ short f2bf(float f) {
    union { float f; unsigned u; } v; v.f = f;
    unsigned r = v.u + 0x7fffu + ((v.u >> 16) & 1u);
    return (short)(r >> 16);
}

// ws layout (floats): [0:64) C, [64:128) Wd, [128:128+2048) = bf16x8 wfrag[8][64].
__global__ void ig_precompute(
    const float* __restrict__ h,      // N x 64
    const float* __restrict__ ghs,    // 64
    const float* __restrict__ goal,   // N x 2
    const float* __restrict__ pos,    // N x 2
    const float* __restrict__ W_emb,  // 32 x 2
    const float* __restrict__ b_emb,  // 32
    const float* __restrict__ W_fc,   // 64 x 192
    const float* __restrict__ b_fc,   // 64
    const int*   __restrict__ idx_p,
    float* __restrict__ out_goal,     // 64
    float* __restrict__ ws)
{
    const int l = threadIdx.x;        // 0..63
    if (l >= 64) return;
    const int idx = idx_p[0];
    const int m15 = l & 15, q = l >> 4;

    // --- C[l], Wd[l], goal_out[l] ---
    const float* wrow = W_fc + l * 192;
    const f32x4* w4  = (const f32x4*)wrow;
    const f32x4* wg4 = (const f32x4*)(wrow + AH);
    const f32x4* h4  = (const f32x4*)(h + (size_t)idx * AH);
    const f32x4* g4  = (const f32x4*)ghs;
    float c = b_fc[l], g = b_fc[l];
    #pragma unroll
    for (int m = 0; m < 16; ++m) {
        const f32x4 hv = h4[m], wv = w4[m];
        const float d = hv[0]*wv[0] + hv[1]*wv[1] + hv[2]*wv[2] + hv[3]*wv[3];
        c += d; g += d;
        const f32x4 gv = g4[m], wv2 = wg4[m];
        g += gv[0]*wv2[0] + gv[1]*wv2[1] + gv[2]*wv2[2] + gv[3]*wv2[3];
    }
    const float px = pos[(size_t)idx*2+0], py = pos[(size_t)idx*2+1];
    const float gx = goal[(size_t)idx*2+0], gy = goal[(size_t)idx*2+1];
    const float dgx = px - gx, dgy = py - gy;
    const float dg = sqrtf(dgx*dgx + dgy*dgy);
    const float* wd1 = wrow + 128;
    const float* wd2 = wrow + 160;
    float wd = 0.f;
    #pragma unroll
    for (int k = 0; k < AD; ++k) {
        const float wsum = W_emb[2*k] + W_emb[2*k+1];
        const float be   = b_emb[k];
        const float w12  = wd1[k] + wd2[k];
        c  += be * w12;
        wd += wsum * wd2[k];
        g  += (dg * wsum + be) * w12;
    }
    ws[l]      = c;
    ws[64 + l] = wd;
    out_goal[l] = sigmoid_fast(g);

    // --- weight A-frags: wfrag[f=mg*2+cc][lane] = W2[mg*16+m15][cc*32+q*8 .. +7] ---
    bf16x8* wf = (bf16x8*)(ws + 128);
    #pragma unroll
    for (int f = 0; f < 8; ++f) {
        const int mg = f >> 1, cc = f & 1;
        const float* src = W_fc + (size_t)(mg*16 + m15) * 192 + AH + cc*32 + q*8;
        const f32x4 s0 = *(const f32x4*)(src);
        const f32x4 s1 = *(const f32x4*)(src + 4);
        bf16x8 b;
        #pragma unroll
        for (int j = 0; j < 4; ++j) { b[j] = f2bf(s0[j]); b[4+j] = f2bf(s1[j]); }
        wf[f * 64 + l] = b;
    }
}

__global__ __launch_bounds__(256, 4) void ig_main(
    const float* __restrict__ h,      // N x 64
    const float* __restrict__ goal,   // N x 2
    const float* __restrict__ pos,    // N x 2
    const float* __restrict__ ws,     // C, Wd, wfrag
    const int*   __restrict__ idx_p,
    float* __restrict__ out,          // N x 64
    int n_tiles, int total_waves)
{
    __shared__ bf16x8 wlds[8][64];              // 8 KB
    __shared__ __align__(16) float cw[128];     // C, Wd

    const int tid  = threadIdx.x;
    const int w    = tid >> 6;
    const int lane = tid & 63;
    const int m15  = lane & 15;
    const int q    = lane >> 4;
    const int idx  = idx_p[0];

    // Stage ws -> LDS: 128 floats + 512 x 16B chunks.
    if (tid < 128) cw[tid] = ws[tid];
    {
        const f32x4* src = (const f32x4*)(ws + 128);
        f32x4* dst = (f32x4*)wlds;
        dst[tid]       = src[tid];
        dst[tid + 256] = src[tid + 256];
    }
    __syncthreads();

    const int wid = blockIdx.x * 4 + w;
    int t = wid;
    f32x4 b0 = {}, b1 = {}, b2 = {}, b3 = {};
    f32x2 gv = {}, pv = {};
    if (t < n_tiles) {
        const int n0 = t * 16 + m15;
        const float* hr = h + (size_t)n0 * AH;
        b0 = *(const f32x4*)(hr + q*8);
        b1 = *(const f32x4*)(hr + q*8 + 4);
        b2 = *(const f32x4*)(hr + 32 + q*8);
        b3 = *(const f32x4*)(hr + 32 + q*8 + 4);
        gv = *(const f32x2*)(goal + 2*(size_t)n0);
        pv = *(const f32x2*)(pos  + 2*(size_t)n0);
    }

    while (t < n_tiles) {
        const int tn = t + total_waves;
        const int tload = (tn < n_tiles) ? tn : t;
        const int nl = tload * 16 + m15;
        const float* hrn = h + (size_t)nl * AH;
        // Prefetch loads issue BEFORE this iteration's stores -> waiting for
        // them next iteration does not drain the stores (in-order vmcnt).
        const f32x4 nb0 = *(const f32x4*)(hrn + q*8);
        const f32x4 nb1 = *(const f32x4*)(hrn + q*8 + 4);
        const f32x4 nb2 = *(const f32x4*)(hrn + 32 + q*8);
        const f32x4 nb3 = *(const f32x4*)(hrn + 32 + q*8 + 4);
        const f32x2 ngv = *(const f32x2*)(goal + 2*(size_t)nl);
        const f32x2 npv = *(const f32x2*)(pos  + 2*(size_t)nl);

        const int agent = t * 16 + m15;
        const float dx = gv[0] - pv[0], dy = gv[1] - pv[1];
        const float d2v = sqrtf(dx*dx + dy*dy);

        bf16x8 bf0, bf1;
        #pragma unroll
        for (int j = 0; j < 4; ++j) {
            bf0[j] = f2bf(b0[j]); bf0[4+j] = f2bf(b1[j]);
            bf1[j] = f2bf(b2[j]); bf1[4+j] = f2bf(b3[j]);
        }

        const size_t rb = (size_t)agent * AH;
        #pragma unroll
        for (int mg = 0; mg < 4; ++mg) {
            const f32x4 c4 = *(const f32x4*)&cw[mg*16 + q*4];
            const f32x4 d4 = *(const f32x4*)&cw[64 + mg*16 + q*4];
            f32x4 acc;
            #pragma unroll
            for (int r = 0; r < 4; ++r) acc[r] = c4[r] + d2v * d4[r];
            acc = __builtin_amdgcn_mfma_f32_16x16x32_bf16(wlds[mg*2+0][lane], bf0, acc, 0, 0, 0);
            acc = __builtin_amdgcn_mfma_f32_16x16x32_bf16(wlds[mg*2+1][lane], bf1, acc, 0, 0, 0);

            f32x4 vv;
            #pragma unroll
            for (int r = 0; r < 4; ++r) vv[r] = sigmoid_fast(acc[r]);
            if (agent == idx) vv = *(const f32x4*)(h + rb + mg*16 + q*4);
            *(f32x4*)(out + rb + mg*16 + q*4) = vv;   // plain cached store
        }

        t = tn;
        b0 = nb0; b1 = nb1; b2 = nb2; b3 = nb3;
        gv = ngv; pv = npv;
    }
}

extern "C" void kernel_launch(void* const* d_in, const int* in_sizes, int n_in,
                              void* d_out, int out_size, void* d_ws, size_t ws_size,
                              hipStream_t stream) {
    const float* h     = (const float*)d_in[0];
    const float* ghs   = (const float*)d_in[1];
    const float* goal  = (const float*)d_in[2];
    const float* pos   = (const float*)d_in[3];
    const float* W_emb = (const float*)d_in[4];
    const float* b_emb = (const float*)d_in[5];
    const float* W_fc  = (const float*)d_in[6];
    const float* b_fc  = (const float*)d_in[7];
    const int*   idx_p = (const int*)d_in[8];

    const int N = in_sizes[0] / AH;          // 500000
    float* out      = (float*)d_out;
    float* out_goal = out + (size_t)N * AH;
    float* ws       = (float*)d_ws;          // 128 + 512*4 floats = 8.5 KB

    ig_precompute<<<1, 64, 0, stream>>>(h, ghs, goal, pos, W_emb, b_emb, W_fc, b_fc,
                                        idx_p, out_goal, ws);

    const int n_tiles = N / 16;              // 31250
    const int blocks = 1024;                 // exact 4 blocks/CU fit
    const int total_waves = blocks * 4;
    ig_main<<<blocks, 256, 0, stream>>>(h, goal, pos, ws, idx_p, out,
                                        n_tiles, total_waves);
}